// Round 2
// baseline (449.168 us; speedup 1.0000x reference)
//
#include <hip/hip_runtime.h>
#include <hip/hip_bf16.h>
#include <stdint.h>

#define H_DIM 4096
#define NH 32
#define HD 128
#define SEQ 1024
#define CTX 4096
#define KVL (CTX + SEQ)      // 5120
#define W3H (3 * H_DIM)      // 12288
#define ATTN_SCALE 0.08838834764831845f

typedef short short8 __attribute__((ext_vector_type(8)));
typedef float f32x4 __attribute__((ext_vector_type(4)));

// async global->LDS, 16B per lane; LDS dest must be wave-uniform base (HW adds lane*16)
#define GLOAD_LDS16(g, l)                                             \
  __builtin_amdgcn_global_load_lds(                                   \
      (const __attribute__((address_space(1))) void*)(g),             \
      (__attribute__((address_space(3))) void*)(l), 16, 0, 0)

__device__ __forceinline__ unsigned short f2b(float f) {
  union { float f; unsigned u; } v; v.f = f;
  return (unsigned short)((v.u + 0x7FFFu + ((v.u >> 16) & 1u)) >> 16);
}

// ---------------- f32 -> bf16 convert (vectorized) ----------------
__global__ void k_cvt(const float* __restrict__ s, unsigned short* __restrict__ d, int n4) {
  int i = blockIdx.x * blockDim.x + threadIdx.x;
  if (i >= n4) return;
  float4 v = reinterpret_cast<const float4*>(s)[i];
  ushort4 o;
  o.x = f2b(v.x); o.y = f2b(v.y); o.z = f2b(v.z); o.w = f2b(v.w);
  reinterpret_cast<ushort4*>(d)[i] = o;
}

// ---------------- QKV GEMM: C[m][n] = sum_k A[m][k]*B[n][k] ----------------
#define BM 128
#define BN 128
#define BK 64
__global__ __launch_bounds__(256, 2) void k_gemm_qkv(
    const unsigned short* __restrict__ A,
    const unsigned short* __restrict__ B,
    unsigned short* __restrict__ C) {
  __shared__ unsigned short As[BM * BK];
  __shared__ unsigned short Bs[BN * BK];
  const int tid = threadIdx.x;
  const int lane = tid & 63;
  const int wid = tid >> 6;
  const int bn = blockIdx.x, bm = blockIdx.y;
  const int wr = wid >> 1, wc = wid & 1;

  f32x4 acc[4][4] = {};

  const int lrow = lane >> 3;
  const int lcol = (lane & 7) * 8;
  const unsigned short* ga = A + (size_t)(bm * BM + wid * 32 + lrow) * H_DIM + lcol;
  const unsigned short* gb = B + (size_t)(bn * BN + wid * 32 + lrow) * H_DIM + lcol;

  for (int kt = 0; kt < H_DIM / BK; ++kt) {
    __syncthreads();
    const unsigned short* gak = ga + kt * BK;
    const unsigned short* gbk = gb + kt * BK;
#pragma unroll
    for (int i = 0; i < 4; ++i) {
      GLOAD_LDS16(gak + i * 8 * H_DIM, As + (wid * 4 + i) * 512);
      GLOAD_LDS16(gbk + i * 8 * H_DIM, Bs + (wid * 4 + i) * 512);
    }
    __syncthreads();
#pragma unroll
    for (int kk = 0; kk < 2; ++kk) {
      short8 af[4], bfr[4];
#pragma unroll
      for (int m = 0; m < 4; ++m)
        af[m] = *reinterpret_cast<const short8*>(
            As + (wr * 64 + m * 16 + (lane & 15)) * BK + kk * 32 + (lane >> 4) * 8);
#pragma unroll
      for (int n = 0; n < 4; ++n)
        bfr[n] = *reinterpret_cast<const short8*>(
            Bs + (wc * 64 + n * 16 + (lane & 15)) * BK + kk * 32 + (lane >> 4) * 8);
#pragma unroll
      for (int m = 0; m < 4; ++m)
#pragma unroll
        for (int n = 0; n < 4; ++n)
          acc[m][n] = __builtin_amdgcn_mfma_f32_16x16x32_bf16(af[m], bfr[n], acc[m][n], 0, 0, 0);
    }
  }
  const int r0 = bm * BM + wr * 64 + (lane >> 4) * 4;
  const int c0 = bn * BN + wc * 64 + (lane & 15);
#pragma unroll
  for (int m = 0; m < 4; ++m)
#pragma unroll
    for (int n = 0; n < 4; ++n)
#pragma unroll
      for (int r = 0; r < 4; ++r)
        C[(size_t)(r0 + m * 16 + r) * W3H + c0 + n * 16] = f2b(acc[m][n][r]);
}

// ---------------- build Kb[h][kv][d] bf16 ----------------
__global__ void k_build_k(const float* __restrict__ cK, const unsigned short* __restrict__ QKV,
                          unsigned short* __restrict__ Kb) {
  int idx = (blockIdx.x * 256 + threadIdx.x) * 4;
  if (idx >= NH * KVL * HD) return;
  int h = idx / (KVL * HD);
  int rem = idx % (KVL * HD);
  int kv = rem / HD;
  int d = rem % HD;
  ushort4 o;
  if (kv < CTX) {
    float4 v = *reinterpret_cast<const float4*>(cK + ((size_t)kv * NH + h) * HD + d);
    o.x = f2b(v.x); o.y = f2b(v.y); o.z = f2b(v.z); o.w = f2b(v.w);
  } else {
    o = *reinterpret_cast<const ushort4*>(QKV + (size_t)(kv - CTX) * W3H + H_DIM + h * HD + d);
  }
  *reinterpret_cast<ushort4*>(Kb + idx) = o;
}

// ---------------- build Vt[h][d][kv] bf16 (transposed) ----------------
__global__ void k_build_vt(const float* __restrict__ cV, const unsigned short* __restrict__ QKV,
                           unsigned short* __restrict__ Vt) {
  __shared__ unsigned short T[HD][66];
  const int h = blockIdx.y;
  const int kt = blockIdx.x;
  const int t = threadIdx.x;
#pragma unroll
  for (int e = 0; e < 8; ++e) {
    int idx = (t + e * 256) * 4;
    int kvl = idx >> 7;
    int d = idx & 127;
    int kv = kt * 64 + kvl;
    unsigned short a, b, c, w;
    if (kv < CTX) {
      float4 v = *reinterpret_cast<const float4*>(cV + ((size_t)kv * NH + h) * HD + d);
      a = f2b(v.x); b = f2b(v.y); c = f2b(v.z); w = f2b(v.w);
    } else {
      ushort4 u = *reinterpret_cast<const ushort4*>(QKV + (size_t)(kv - CTX) * W3H + 2 * H_DIM + h * HD + d);
      a = u.x; b = u.y; c = u.z; w = u.w;
    }
    T[d][kvl] = a; T[d + 1][kvl] = b; T[d + 2][kvl] = c; T[d + 3][kvl] = w;
  }
  __syncthreads();
#pragma unroll
  for (int e = 0; e < 8; ++e) {
    int idx = (t + e * 256) * 4;
    int d = idx >> 6;
    int kv0 = idx & 63;
    ushort4 o;
    o.x = T[d][kv0]; o.y = T[d][kv0 + 1]; o.z = T[d][kv0 + 2]; o.w = T[d][kv0 + 3];
    *reinterpret_cast<ushort4*>(Vt + ((size_t)h * HD + d) * KVL + kt * 64 + kv0) = o;
  }
}

// ---------------- flash attention (double-buffered, XCD head-grouped) ----------------
#define KVT 64
#define NT (KVL / KVT)   // 80
#define PPAD 76
__global__ __launch_bounds__(256, 2) void k_attn(
    const unsigned short* __restrict__ QKV,
    const unsigned short* __restrict__ Kb,
    const unsigned short* __restrict__ Vt,
    float* __restrict__ O) {
  __shared__ unsigned short Ks[2][KVT * HD];  // 2x16KB, swizzled
  __shared__ unsigned short Vs[2][HD * KVT];  // 2x16KB, swizzled
  __shared__ unsigned short Ps[4][16 * PPAD];
  const int tid = threadIdx.x, lane = tid & 63, wid = tid >> 6;
  // XCD head-grouping: all 16 q-tiles of a head on one XCD (id%8 -> XCD)
  const int id = blockIdx.x;
  const int xcd = id & 7, slot = id >> 3;
  const int h = xcd * 4 + (slot >> 4);
  const int qt = slot & 15;
  const int q0 = qt * 64 + wid * 16;

  short8 qf[4];
#pragma unroll
  for (int c = 0; c < 4; ++c)
    qf[c] = *reinterpret_cast<const short8*>(
        QKV + (size_t)(q0 + (lane & 15)) * W3H + h * HD + c * 32 + (lane >> 4) * 8);

  float m_r[4], l_r[4];
  f32x4 acc_o[8] = {};
#pragma unroll
  for (int r = 0; r < 4; ++r) { m_r[r] = -1e30f; l_r[r] = 0.f; }

  const char* Kh = (const char*)(Kb + (size_t)h * KVL * HD);
  const char* Vh = (const char*)(Vt + (size_t)h * HD * KVL);
  unsigned short* Pw = &Ps[wid][0];

  // per-wave stage of tile t into buffer b (8 x 16B-per-lane loads)
#define STAGE(t, b)                                                            \
  {                                                                            \
    _Pragma("unroll") for (int i = 0; i < 4; ++i) {                            \
      int c = wid * 4 + i;                                                     \
      int krow = c * 4 + (lane >> 4);                                          \
      int klcb = (16 * (lane & 15)) ^ ((krow & 7) << 4);                       \
      GLOAD_LDS16(Kh + (size_t)((t) * KVT + krow) * 256 + klcb,                \
                  (char*)Ks[b] + c * 1024);                                    \
      int vrow = c * 8 + (lane >> 3);                                          \
      int vlcb = (16 * (lane & 7)) ^ ((vrow & 7) << 4);                        \
      GLOAD_LDS16(Vh + (size_t)vrow * (KVL * 2) + (size_t)(t) * (KVT * 2) + vlcb, \
                  (char*)Vs[b] + c * 1024);                                    \
    }                                                                          \
  }

  STAGE(0, 0);
  __syncthreads();  // drain vmcnt; tile 0 visible

  for (int kt = 0; kt < NT; ++kt) {
    const int cur = kt & 1;
    if (kt + 1 < NT) STAGE(kt + 1, cur ^ 1);  // issue early; latency hides under compute

    // S = Q K^T  (16q x 64kv per wave)
    f32x4 s[4] = {};
#pragma unroll
    for (int n = 0; n < 4; ++n) {
      int row = n * 16 + (lane & 15);
#pragma unroll
      for (int c = 0; c < 4; ++c) {
        int cb = (c * 32 + (lane >> 4) * 8) * 2;
        short8 kf = *reinterpret_cast<const short8*>(
            (const char*)Ks[cur] + row * 256 + (cb ^ ((row & 7) << 4)));
        s[n] = __builtin_amdgcn_mfma_f32_16x16x32_bf16(qf[c], kf, s[n], 0, 0, 0);
      }
    }

    // online softmax over this tile's 64 cols (scaled-logit domain)
    float p[4][4];
#pragma unroll
    for (int n = 0; n < 4; ++n)
#pragma unroll
      for (int r = 0; r < 4; ++r) p[n][r] = s[n][r] * ATTN_SCALE;
#pragma unroll
    for (int r = 0; r < 4; ++r) {
      float t0 = fmaxf(fmaxf(p[0][r], p[1][r]), fmaxf(p[2][r], p[3][r]));
#pragma unroll
      for (int off = 1; off < 16; off <<= 1) t0 = fmaxf(t0, __shfl_xor(t0, off, 64));
      float mn = fmaxf(m_r[r], t0);
      float alpha = __expf(m_r[r] - mn);
      float sum = 0.f;
#pragma unroll
      for (int n = 0; n < 4; ++n) {
        p[n][r] = __expf(p[n][r] - mn);
        sum += p[n][r];
      }
#pragma unroll
      for (int off = 1; off < 16; off <<= 1) sum += __shfl_xor(sum, off, 64);
      l_r[r] = l_r[r] * alpha + sum;
      m_r[r] = mn;
#pragma unroll
      for (int nd = 0; nd < 8; ++nd) acc_o[nd][r] *= alpha;
    }

    // P -> LDS (per-wave; PPAD=76 -> conflict-free writes)
#pragma unroll
    for (int n = 0; n < 4; ++n)
#pragma unroll
      for (int r = 0; r < 4; ++r)
        Pw[((lane >> 4) * 4 + r) * PPAD + n * 16 + (lane & 15)] = f2b(p[n][r]);

    // O += P V
#pragma unroll
    for (int kc = 0; kc < 2; ++kc) {
      short8 pf = *reinterpret_cast<const short8*>(
          Pw + (lane & 15) * PPAD + kc * 32 + (lane >> 4) * 8);
#pragma unroll
      for (int nd = 0; nd < 8; ++nd) {
        int row = nd * 16 + (lane & 15);
        int cb = kc * 64 + (lane >> 4) * 16;
        short8 vf = *reinterpret_cast<const short8*>(
            (const char*)Vs[cur] + row * 128 + (cb ^ ((row & 7) << 4)));
        acc_o[nd] = __builtin_amdgcn_mfma_f32_16x16x32_bf16(pf, vf, acc_o[nd], 0, 0, 0);
      }
    }

    __syncthreads();  // drains vmcnt(0): tile kt+1 staged & visible; buffers safe to swap
  }

  // epilogue
  float inv[4];
#pragma unroll
  for (int r = 0; r < 4; ++r) inv[r] = 1.0f / l_r[r];
#pragma unroll
  for (int nd = 0; nd < 8; ++nd)
#pragma unroll
    for (int r = 0; r < 4; ++r)
      O[(size_t)(q0 + (lane >> 4) * 4 + r) * H_DIM + h * HD + nd * 16 + (lane & 15)] =
          acc_o[nd][r] * inv[r];
#undef STAGE
}

extern "C" void kernel_launch(void* const* d_in, const int* in_sizes, int n_in,
                              void* d_out, int out_size, void* d_ws, size_t ws_size,
                              hipStream_t stream) {
  const float* X = (const float*)d_in[0];
  const float* W = (const float*)d_in[1];
  const float* cK = (const float*)d_in[2];
  const float* cV = (const float*)d_in[3];
  float* out = (float*)d_out;
  char* ws = (char*)d_ws;

  unsigned short* Xb = (unsigned short*)(ws);
  unsigned short* QKVb = (unsigned short*)(ws + ((size_t)8 << 20));
  unsigned short* Wb = (unsigned short*)(ws + ((size_t)32 << 20));
  unsigned short* Kb = (unsigned short*)(ws + ((size_t)32 << 20));
  unsigned short* Vt = (unsigned short*)(ws + ((size_t)72 << 20));

  k_cvt<<<(SEQ * H_DIM / 4) / 256, 256, 0, stream>>>(X, Xb, SEQ * H_DIM / 4);
  k_cvt<<<(W3H * H_DIM / 4) / 256, 256, 0, stream>>>(W, Wb, W3H * H_DIM / 4);

  dim3 gg(W3H / BN, SEQ / BM);
  k_gemm_qkv<<<gg, 256, 0, stream>>>(Xb, Wb, QKVb);

  k_build_k<<<(NH * KVL * HD / 4) / 256, 256, 0, stream>>>(cK, QKVb, Kb);
  dim3 gv(KVL / 64, NH);
  k_build_vt<<<gv, 256, 0, stream>>>(cV, QKVb, Vt);

  k_attn<<<SEQ / 64 * NH, 256, 0, stream>>>(QKVb, Kb, Vt, out);
}

// Round 4
// 439.773 us; speedup vs baseline: 1.0214x; 1.0214x over previous
//
#include <hip/hip_runtime.h>
#include <hip/hip_bf16.h>
#include <stdint.h>

#define H_DIM 4096
#define NH 32
#define HD 128
#define SEQ 1024
#define CTX 4096
#define KVL (CTX + SEQ)      // 5120
#define W3H (3 * H_DIM)      // 12288
#define ATTN_SCALE 0.08838834764831845f

typedef short short8 __attribute__((ext_vector_type(8)));
typedef float f32x4 __attribute__((ext_vector_type(4)));

// async global->LDS, 16B per lane; LDS dest must be wave-uniform base (HW adds lane*16)
#define GLOAD_LDS16(g, l)                                             \
  __builtin_amdgcn_global_load_lds(                                   \
      (const __attribute__((address_space(1))) void*)(g),             \
      (__attribute__((address_space(3))) void*)(l), 16, 0, 0)

__device__ __forceinline__ unsigned short f2b(float f) {
  union { float f; unsigned u; } v; v.f = f;
  return (unsigned short)((v.u + 0x7FFFu + ((v.u >> 16) & 1u)) >> 16);
}
__device__ __forceinline__ float b2f(unsigned short u) {
  union { unsigned u; float f; } v; v.u = ((unsigned)u) << 16;
  return v.f;
}

// ---------------- f32 -> bf16 convert (vectorized) ----------------
__global__ void k_cvt(const float* __restrict__ s, unsigned short* __restrict__ d, int n4) {
  int i = blockIdx.x * blockDim.x + threadIdx.x;
  if (i >= n4) return;
  float4 v = reinterpret_cast<const float4*>(s)[i];
  ushort4 o;
  o.x = f2b(v.x); o.y = f2b(v.y); o.z = f2b(v.z); o.w = f2b(v.w);
  reinterpret_cast<ushort4*>(d)[i] = o;
}

// ---------------- QKV GEMM: C[m][n] = sum_k A[m][k]*B[n][k] ----------------
#define BM 128
#define BN 128
#define BK 64
__global__ __launch_bounds__(256, 2) void k_gemm_qkv(
    const unsigned short* __restrict__ A,
    const unsigned short* __restrict__ B,
    unsigned short* __restrict__ C) {
  __shared__ unsigned short As[BM * BK];
  __shared__ unsigned short Bs[BN * BK];
  const int tid = threadIdx.x;
  const int lane = tid & 63;
  const int wid = tid >> 6;
  const int bn = blockIdx.x, bm = blockIdx.y;
  const int wr = wid >> 1, wc = wid & 1;

  f32x4 acc[4][4] = {};

  const int lrow = lane >> 3;
  const int lcol = (lane & 7) * 8;
  const unsigned short* ga = A + (size_t)(bm * BM + wid * 32 + lrow) * H_DIM + lcol;
  const unsigned short* gb = B + (size_t)(bn * BN + wid * 32 + lrow) * H_DIM + lcol;

  for (int kt = 0; kt < H_DIM / BK; ++kt) {
    __syncthreads();
    const unsigned short* gak = ga + kt * BK;
    const unsigned short* gbk = gb + kt * BK;
#pragma unroll
    for (int i = 0; i < 4; ++i) {
      GLOAD_LDS16(gak + i * 8 * H_DIM, As + (wid * 4 + i) * 512);
      GLOAD_LDS16(gbk + i * 8 * H_DIM, Bs + (wid * 4 + i) * 512);
    }
    __syncthreads();
#pragma unroll
    for (int kk = 0; kk < 2; ++kk) {
      short8 af[4], bfr[4];
#pragma unroll
      for (int m = 0; m < 4; ++m)
        af[m] = *reinterpret_cast<const short8*>(
            As + (wr * 64 + m * 16 + (lane & 15)) * BK + kk * 32 + (lane >> 4) * 8);
#pragma unroll
      for (int n = 0; n < 4; ++n)
        bfr[n] = *reinterpret_cast<const short8*>(
            Bs + (wc * 64 + n * 16 + (lane & 15)) * BK + kk * 32 + (lane >> 4) * 8);
#pragma unroll
      for (int m = 0; m < 4; ++m)
#pragma unroll
        for (int n = 0; n < 4; ++n)
          acc[m][n] = __builtin_amdgcn_mfma_f32_16x16x32_bf16(af[m], bfr[n], acc[m][n], 0, 0, 0);
    }
  }
  const int r0 = bm * BM + wr * 64 + (lane >> 4) * 4;
  const int c0 = bn * BN + wc * 64 + (lane & 15);
#pragma unroll
  for (int m = 0; m < 4; ++m)
#pragma unroll
    for (int n = 0; n < 4; ++n)
#pragma unroll
      for (int r = 0; r < 4; ++r)
        C[(size_t)(r0 + m * 16 + r) * W3H + c0 + n * 16] = f2b(acc[m][n][r]);
}

// ---------------- build Kb[h][kv][d] bf16 ----------------
__global__ void k_build_k(const float* __restrict__ cK, const unsigned short* __restrict__ QKV,
                          unsigned short* __restrict__ Kb) {
  int idx = (blockIdx.x * 256 + threadIdx.x) * 4;
  if (idx >= NH * KVL * HD) return;
  int h = idx / (KVL * HD);
  int rem = idx % (KVL * HD);
  int kv = rem / HD;
  int d = rem % HD;
  ushort4 o;
  if (kv < CTX) {
    float4 v = *reinterpret_cast<const float4*>(cK + ((size_t)kv * NH + h) * HD + d);
    o.x = f2b(v.x); o.y = f2b(v.y); o.z = f2b(v.z); o.w = f2b(v.w);
  } else {
    o = *reinterpret_cast<const ushort4*>(QKV + (size_t)(kv - CTX) * W3H + H_DIM + h * HD + d);
  }
  *reinterpret_cast<ushort4*>(Kb + idx) = o;
}

// ---------------- build Vt[h][d][kv] bf16 (transposed) ----------------
__global__ void k_build_vt(const float* __restrict__ cV, const unsigned short* __restrict__ QKV,
                           unsigned short* __restrict__ Vt) {
  __shared__ unsigned short T[HD][66];
  const int h = blockIdx.y;
  const int kt = blockIdx.x;
  const int t = threadIdx.x;
#pragma unroll
  for (int e = 0; e < 8; ++e) {
    int idx = (t + e * 256) * 4;
    int kvl = idx >> 7;
    int d = idx & 127;
    int kv = kt * 64 + kvl;
    unsigned short a, b, c, w;
    if (kv < CTX) {
      float4 v = *reinterpret_cast<const float4*>(cV + ((size_t)kv * NH + h) * HD + d);
      a = f2b(v.x); b = f2b(v.y); c = f2b(v.z); w = f2b(v.w);
    } else {
      ushort4 u = *reinterpret_cast<const ushort4*>(QKV + (size_t)(kv - CTX) * W3H + 2 * H_DIM + h * HD + d);
      a = u.x; b = u.y; c = u.z; w = u.w;
    }
    T[d][kvl] = a; T[d + 1][kvl] = b; T[d + 2][kvl] = c; T[d + 3][kvl] = w;
  }
  __syncthreads();
#pragma unroll
  for (int e = 0; e < 8; ++e) {
    int idx = (t + e * 256) * 4;
    int d = idx >> 6;
    int kv0 = idx & 63;
    ushort4 o;
    o.x = T[d][kv0]; o.y = T[d][kv0 + 1]; o.z = T[d][kv0 + 2]; o.w = T[d][kv0 + 3];
    *reinterpret_cast<ushort4*>(Vt + ((size_t)h * HD + d) * KVL + kt * 64 + kv0) = o;
  }
}

// ---------------- flash attention (split-KV=2, reg-staged single LDS buffer) ----------------
#define KVT 64
#define NT (KVL / KVT)   // 80
#define NT2 (NT / 2)     // 40 per split
#define PPAD 76
__global__ __launch_bounds__(256, 3) void k_attn(
    const unsigned short* __restrict__ QKV,
    const unsigned short* __restrict__ Kb,
    const unsigned short* __restrict__ Vt,
    float* __restrict__ A0,      // split-0 unnormalized partial [SEQ][H_DIM]
    float* __restrict__ A1,      // split-1 unnormalized partial
    float* __restrict__ Mp,      // [2][NH][SEQ] running max
    float* __restrict__ Lp) {    // [2][NH][SEQ] running sum
  __shared__ unsigned short Ks[KVT * HD];  // 16KB, swizzled
  __shared__ unsigned short Vs[HD * KVT];  // 16KB, swizzled
  __shared__ unsigned short Ps[4][16 * PPAD];
  const int tid = threadIdx.x, lane = tid & 63, wid = tid >> 6;
  // XCD head-grouping: 4 heads per XCD; both splits of a (h,qt) adjacent
  const int id = blockIdx.x;
  const int xcd = id & 7, slot = id >> 3;       // slot 0..127
  const int h = xcd * 4 + (slot >> 5);
  const int rem = slot & 31;
  const int qt = rem >> 1;
  const int split = rem & 1;
  const int kt0 = split * NT2;
  const int q0 = qt * 64 + wid * 16;

  // Q fragments, pre-scaled by 1/sqrt(d)
  short8 qf[4];
#pragma unroll
  for (int c = 0; c < 4; ++c) {
    short8 q = *reinterpret_cast<const short8*>(
        QKV + (size_t)(q0 + (lane & 15)) * W3H + h * HD + c * 32 + (lane >> 4) * 8);
    short8 t;
#pragma unroll
    for (int j = 0; j < 8; ++j) t[j] = (short)f2b(b2f((unsigned short)q[j]) * ATTN_SCALE);
    qf[c] = t;
  }

  float m_r[4], l_r[4];
  f32x4 acc_o[8] = {};
#pragma unroll
  for (int r = 0; r < 4; ++r) { m_r[r] = -1e30f; l_r[r] = 0.f; }

  const char* Kh = (const char*)(Kb + (size_t)h * KVL * HD);
  const char* Vh = (const char*)(Vt + (size_t)h * HD * KVL);
  unsigned short* Pw = &Ps[wid][0];

  short8 rK[4], rV[4];  // reg-staged next tile (pre-swizzled source addressing)

#define LOADR(t)                                                               \
  {                                                                            \
    _Pragma("unroll") for (int i = 0; i < 4; ++i) {                            \
      int c = wid * 4 + i;                                                     \
      int krow = c * 4 + (lane >> 4);                                          \
      int klcb = (16 * (lane & 15)) ^ ((krow & 7) << 4);                       \
      rK[i] = *reinterpret_cast<const short8*>(                                \
          Kh + (size_t)((t) * KVT + krow) * 256 + klcb);                       \
      int vrow = c * 8 + (lane >> 3);                                          \
      int vlcb = (16 * (lane & 7)) ^ ((vrow & 7) << 4);                        \
      rV[i] = *reinterpret_cast<const short8*>(                                \
          Vh + (size_t)vrow * (KVL * 2) + (size_t)(t) * 128 + vlcb);           \
    }                                                                          \
  }
#define WRITE_LDS()                                                            \
  {                                                                            \
    _Pragma("unroll") for (int i = 0; i < 4; ++i) {                            \
      *reinterpret_cast<short8*>((char*)Ks + (wid * 4 + i) * 1024 + lane * 16) = rK[i]; \
      *reinterpret_cast<short8*>((char*)Vs + (wid * 4 + i) * 1024 + lane * 16) = rV[i]; \
    }                                                                          \
  }

  LOADR(kt0);
  WRITE_LDS();          // compiler inserts vmcnt wait on data dep
  __syncthreads();      // tile kt0 visible

  for (int kt = 0; kt < NT2; ++kt) {
    if (kt + 1 < NT2) LOADR(kt0 + kt + 1);  // in flight across the compute phase

    // S = Q K^T  (16q x 64kv per wave); q = (lane>>4)*4+r, kv = n*16 + (lane&15)
    f32x4 s[4] = {};
#pragma unroll
    for (int n = 0; n < 4; ++n) {
      int row = n * 16 + (lane & 15);
#pragma unroll
      for (int c = 0; c < 4; ++c) {
        int cb = (c * 32 + (lane >> 4) * 8) * 2;
        short8 kf = *reinterpret_cast<const short8*>(
            (const char*)Ks + row * 256 + (cb ^ ((row & 7) << 4)));
        s[n] = __builtin_amdgcn_mfma_f32_16x16x32_bf16(qf[c], kf, s[n], 0, 0, 0);
      }
    }

    // online softmax (logits already scaled); defer-max with THR=8
    float p[4][4], tmax[4];
    int ok = 1;
#pragma unroll
    for (int r = 0; r < 4; ++r) {
      float t0 = fmaxf(fmaxf(s[0][r], s[1][r]), fmaxf(s[2][r], s[3][r]));
#pragma unroll
      for (int off = 1; off < 16; off <<= 1) t0 = fmaxf(t0, __shfl_xor(t0, off, 64));
      tmax[r] = t0;
      ok &= (t0 <= m_r[r] + 8.0f);
    }
    if (!__all(ok)) {
#pragma unroll
      for (int r = 0; r < 4; ++r) {
        float mn = fmaxf(m_r[r], tmax[r]);
        float alpha = __expf(m_r[r] - mn);
        l_r[r] *= alpha;
        m_r[r] = mn;
#pragma unroll
        for (int nd = 0; nd < 8; ++nd) acc_o[nd][r] *= alpha;
      }
    }
#pragma unroll
    for (int r = 0; r < 4; ++r) {
      float sum = 0.f;
#pragma unroll
      for (int n = 0; n < 4; ++n) {
        p[n][r] = __expf(s[n][r] - m_r[r]);
        sum += p[n][r];
      }
#pragma unroll
      for (int off = 1; off < 16; off <<= 1) sum += __shfl_xor(sum, off, 64);
      l_r[r] += sum;
    }

    // P -> LDS (per-wave; PPAD=76 -> conflict-free writes)
#pragma unroll
    for (int n = 0; n < 4; ++n)
#pragma unroll
      for (int r = 0; r < 4; ++r)
        Pw[((lane >> 4) * 4 + r) * PPAD + n * 16 + (lane & 15)] = f2b(p[n][r]);

    // O += P V
#pragma unroll
    for (int kc = 0; kc < 2; ++kc) {
      short8 pf = *reinterpret_cast<const short8*>(
          Pw + (lane & 15) * PPAD + kc * 32 + (lane >> 4) * 8);
#pragma unroll
      for (int nd = 0; nd < 8; ++nd) {
        int row = nd * 16 + (lane & 15);
        int cb = kc * 64 + (lane >> 4) * 16;
        short8 vf = *reinterpret_cast<const short8*>(
            (const char*)Vs + row * 128 + (cb ^ ((row & 7) << 4)));
        acc_o[nd] = __builtin_amdgcn_mfma_f32_16x16x32_bf16(pf, vf, acc_o[nd], 0, 0, 0);
      }
    }

    __syncthreads();  // all waves done reading tile kt; rK/rV loads landed under compute
    if (kt + 1 < NT2) {
      WRITE_LDS();
      __syncthreads();  // tile kt+1 visible (only lgkm drain here; no vmem outstanding)
    }
  }

  // epilogue: unnormalized partial + m,l
  float* Op = split ? A1 : A0;
#pragma unroll
  for (int nd = 0; nd < 8; ++nd)
#pragma unroll
    for (int r = 0; r < 4; ++r)
      Op[(size_t)(q0 + (lane >> 4) * 4 + r) * H_DIM + h * HD + nd * 16 + (lane & 15)] =
          acc_o[nd][r];
  if ((lane & 15) == 0) {
#pragma unroll
    for (int r = 0; r < 4; ++r) {
      int q = q0 + (lane >> 4) * 4 + r;
      Mp[split * (NH * SEQ) + h * SEQ + q] = m_r[r];
      Lp[split * (NH * SEQ) + h * SEQ + q] = l_r[r];
    }
  }
#undef LOADR
#undef WRITE_LDS
}

// ---------------- combine the two KV-splits ----------------
__global__ void k_combine(const float* __restrict__ A1, const float* __restrict__ Mp,
                          const float* __restrict__ Lp, float* __restrict__ out) {
  int i4 = blockIdx.x * 256 + threadIdx.x;  // < SEQ*H_DIM/4
  int q = i4 >> 10;                          // H_DIM/4 = 1024 float4 per row
  int c4 = i4 & 1023;
  int h = c4 >> 5;                           // 32 float4 per head
  float m0 = Mp[h * SEQ + q], m1 = Mp[NH * SEQ + h * SEQ + q];
  float l0 = Lp[h * SEQ + q], l1 = Lp[NH * SEQ + h * SEQ + q];
  float M = fmaxf(m0, m1);
  float w0 = __expf(m0 - M), w1 = __expf(m1 - M);
  float inv = 1.0f / (w0 * l0 + w1 * l1);
  float4 a0 = reinterpret_cast<const float4*>(out)[i4];
  float4 a1 = reinterpret_cast<const float4*>(A1)[i4];
  float4 o;
  o.x = (w0 * a0.x + w1 * a1.x) * inv;
  o.y = (w0 * a0.y + w1 * a1.y) * inv;
  o.z = (w0 * a0.z + w1 * a1.z) * inv;
  o.w = (w0 * a0.w + w1 * a1.w) * inv;
  reinterpret_cast<float4*>(out)[i4] = o;
}

extern "C" void kernel_launch(void* const* d_in, const int* in_sizes, int n_in,
                              void* d_out, int out_size, void* d_ws, size_t ws_size,
                              hipStream_t stream) {
  const float* X = (const float*)d_in[0];
  const float* W = (const float*)d_in[1];
  const float* cK = (const float*)d_in[2];
  const float* cV = (const float*)d_in[3];
  float* out = (float*)d_out;
  char* ws = (char*)d_ws;

  // ws: Xb[0,8M) QKVb[8M,32M) Wb/Kb[32M,72M) Vt[72M,112M) A1[112M,128M)
  // Mp/Lp alias Xb's first 512K — Xb is dead after the GEMM, k_attn runs after it,
  // and k_cvt fully rewrites Xb every call => deterministic across replays.
  unsigned short* Xb = (unsigned short*)(ws);
  float* Mp = (float*)(ws);
  float* Lp = (float*)(ws + (256 << 10));
  unsigned short* QKVb = (unsigned short*)(ws + ((size_t)8 << 20));
  unsigned short* Wb = (unsigned short*)(ws + ((size_t)32 << 20));
  unsigned short* Kb = (unsigned short*)(ws + ((size_t)32 << 20));
  unsigned short* Vt = (unsigned short*)(ws + ((size_t)72 << 20));
  float* A1 = (float*)(ws + ((size_t)112 << 20));

  k_cvt<<<(SEQ * H_DIM / 4) / 256, 256, 0, stream>>>(X, Xb, SEQ * H_DIM / 4);
  k_cvt<<<(W3H * H_DIM / 4) / 256, 256, 0, stream>>>(W, Wb, W3H * H_DIM / 4);

  dim3 gg(W3H / BN, SEQ / BM);
  k_gemm_qkv<<<gg, 256, 0, stream>>>(Xb, Wb, QKVb);

  k_build_k<<<(NH * KVL * HD / 4) / 256, 256, 0, stream>>>(cK, QKVb, Kb);
  dim3 gv(KVL / 64, NH);
  k_build_vt<<<gv, 256, 0, stream>>>(cV, QKVb, Vt);

  k_attn<<<SEQ / 64 * NH * 2, 256, 0, stream>>>(QKVb, Kb, Vt, out, A1, Mp, Lp);
  k_combine<<<(SEQ * H_DIM / 4) / 256, 256, 0, stream>>>(A1, Mp, Lp, out);
}

// Round 6
// 388.394 us; speedup vs baseline: 1.1565x; 1.1323x over previous
//
#include <hip/hip_runtime.h>
#include <hip/hip_bf16.h>
#include <stdint.h>

#define H_DIM 4096
#define NH 32
#define HD 128
#define SEQ 1024
#define CTX 4096
#define KVL (CTX + SEQ)      // 5120
#define W3H (3 * H_DIM)      // 12288
#define ATTN_SCALE 0.08838834764831845f

typedef short short8 __attribute__((ext_vector_type(8)));
typedef float f32x4 __attribute__((ext_vector_type(4)));

// async global->LDS, 16B per lane; LDS dest must be wave-uniform base (HW adds lane*16)
#define GLOAD_LDS16(g, l)                                             \
  __builtin_amdgcn_global_load_lds(                                   \
      (const __attribute__((address_space(1))) void*)(g),             \
      (__attribute__((address_space(3))) void*)(l), 16, 0, 0)

__device__ __forceinline__ unsigned short f2b(float f) {
  union { float f; unsigned u; } v; v.f = f;
  return (unsigned short)((v.u + 0x7FFFu + ((v.u >> 16) & 1u)) >> 16);
}
__device__ __forceinline__ float b2f(unsigned short u) {
  union { unsigned u; float f; } v; v.u = ((unsigned)u) << 16;
  return v.f;
}

// ---------------- f32 -> bf16 convert (vectorized) ----------------
__global__ void k_cvt(const float* __restrict__ s, unsigned short* __restrict__ d, int n4) {
  int i = blockIdx.x * blockDim.x + threadIdx.x;
  if (i >= n4) return;
  float4 v = reinterpret_cast<const float4*>(s)[i];
  ushort4 o;
  o.x = f2b(v.x); o.y = f2b(v.y); o.z = f2b(v.z); o.w = f2b(v.w);
  reinterpret_cast<ushort4*>(d)[i] = o;
}

// ---------------- QKV GEMM: C[m][n] = sum_k A[m][k]*B[n][k] ----------------
#define BM 128
#define BN 128
#define BK 64
__global__ __launch_bounds__(256, 2) void k_gemm_qkv(
    const unsigned short* __restrict__ A,
    const unsigned short* __restrict__ B,
    unsigned short* __restrict__ C) {
  __shared__ unsigned short As[BM * BK];
  __shared__ unsigned short Bs[BN * BK];
  const int tid = threadIdx.x;
  const int lane = tid & 63;
  const int wid = tid >> 6;
  const int bn = blockIdx.x, bm = blockIdx.y;
  const int wr = wid >> 1, wc = wid & 1;

  f32x4 acc[4][4] = {};

  const int lrow = lane >> 3;
  const int lcol = (lane & 7) * 8;
  const unsigned short* ga = A + (size_t)(bm * BM + wid * 32 + lrow) * H_DIM + lcol;
  const unsigned short* gb = B + (size_t)(bn * BN + wid * 32 + lrow) * H_DIM + lcol;

  for (int kt = 0; kt < H_DIM / BK; ++kt) {
    __syncthreads();
    const unsigned short* gak = ga + kt * BK;
    const unsigned short* gbk = gb + kt * BK;
#pragma unroll
    for (int i = 0; i < 4; ++i) {
      GLOAD_LDS16(gak + i * 8 * H_DIM, As + (wid * 4 + i) * 512);
      GLOAD_LDS16(gbk + i * 8 * H_DIM, Bs + (wid * 4 + i) * 512);
    }
    __syncthreads();
#pragma unroll
    for (int kk = 0; kk < 2; ++kk) {
      short8 af[4], bfr[4];
#pragma unroll
      for (int m = 0; m < 4; ++m)
        af[m] = *reinterpret_cast<const short8*>(
            As + (wr * 64 + m * 16 + (lane & 15)) * BK + kk * 32 + (lane >> 4) * 8);
#pragma unroll
      for (int n = 0; n < 4; ++n)
        bfr[n] = *reinterpret_cast<const short8*>(
            Bs + (wc * 64 + n * 16 + (lane & 15)) * BK + kk * 32 + (lane >> 4) * 8);
#pragma unroll
      for (int m = 0; m < 4; ++m)
#pragma unroll
        for (int n = 0; n < 4; ++n)
          acc[m][n] = __builtin_amdgcn_mfma_f32_16x16x32_bf16(af[m], bfr[n], acc[m][n], 0, 0, 0);
    }
  }
  const int r0 = bm * BM + wr * 64 + (lane >> 4) * 4;
  const int c0 = bn * BN + wc * 64 + (lane & 15);
#pragma unroll
  for (int m = 0; m < 4; ++m)
#pragma unroll
    for (int n = 0; n < 4; ++n)
#pragma unroll
      for (int r = 0; r < 4; ++r)
        C[(size_t)(r0 + m * 16 + r) * W3H + c0 + n * 16] = f2b(acc[m][n][r]);
}

// ---------------- build Kb[h][kv][d] bf16 ----------------
__global__ void k_build_k(const float* __restrict__ cK, const unsigned short* __restrict__ QKV,
                          unsigned short* __restrict__ Kb) {
  int idx = (blockIdx.x * 256 + threadIdx.x) * 4;
  if (idx >= NH * KVL * HD) return;
  int h = idx / (KVL * HD);
  int rem = idx % (KVL * HD);
  int kv = rem / HD;
  int d = rem % HD;
  ushort4 o;
  if (kv < CTX) {
    float4 v = *reinterpret_cast<const float4*>(cK + ((size_t)kv * NH + h) * HD + d);
    o.x = f2b(v.x); o.y = f2b(v.y); o.z = f2b(v.z); o.w = f2b(v.w);
  } else {
    o = *reinterpret_cast<const ushort4*>(QKV + (size_t)(kv - CTX) * W3H + H_DIM + h * HD + d);
  }
  *reinterpret_cast<ushort4*>(Kb + idx) = o;
}

// ---------------- build Vt[h][d][kv] bf16 (transposed) ----------------
__global__ void k_build_vt(const float* __restrict__ cV, const unsigned short* __restrict__ QKV,
                           unsigned short* __restrict__ Vt) {
  __shared__ unsigned short T[HD][66];
  const int h = blockIdx.y;
  const int kt = blockIdx.x;
  const int t = threadIdx.x;
#pragma unroll
  for (int e = 0; e < 8; ++e) {
    int idx = (t + e * 256) * 4;
    int kvl = idx >> 7;
    int d = idx & 127;
    int kv = kt * 64 + kvl;
    unsigned short a, b, c, w;
    if (kv < CTX) {
      float4 v = *reinterpret_cast<const float4*>(cV + ((size_t)kv * NH + h) * HD + d);
      a = f2b(v.x); b = f2b(v.y); c = f2b(v.z); w = f2b(v.w);
    } else {
      ushort4 u = *reinterpret_cast<const ushort4*>(QKV + (size_t)(kv - CTX) * W3H + 2 * H_DIM + h * HD + d);
      a = u.x; b = u.y; c = u.z; w = u.w;
    }
    T[d][kvl] = a; T[d + 1][kvl] = b; T[d + 2][kvl] = c; T[d + 3][kvl] = w;
  }
  __syncthreads();
#pragma unroll
  for (int e = 0; e < 8; ++e) {
    int idx = (t + e * 256) * 4;
    int d = idx >> 6;
    int kv0 = idx & 63;
    ushort4 o;
    o.x = T[d][kv0]; o.y = T[d][kv0 + 1]; o.z = T[d][kv0 + 2]; o.w = T[d][kv0 + 3];
    *reinterpret_cast<ushort4*>(Vt + ((size_t)h * HD + d) * KVL + kt * 64 + kv0) = o;
  }
}

// ---------------- flash attention (swapped-operand MFMA, in-register P) ----------------
// S^T = mfma(K,Q): lane owns col q=lane&15 -> in-lane softmax, 2 shfl per reduce.
// O^T = mfma(V^T,P^T): alpha/l lane-local; P repacked in-register via bpermute.
// Repack algebra: target (g',qi,kc) needs P[q=qi][kv=kc*32+g'*8+j] =
//   source lane ((g'&1)*2 + (j>=4), qi), register pr[2kc + (g'>>1)][(j&3)>>1].
// ds_bpermute is a PULL (source picks the sent value), and sources serve two
// target groups needing different n-halves -> pull BOTH halves, select by g'>=2.
#define KVT 64
#define NT (KVL / KVT)   // 80
#define NT2 (NT / 2)     // 40 per split
__global__ __launch_bounds__(256, 4) void k_attn(
    const unsigned short* __restrict__ QKV,
    const unsigned short* __restrict__ Kb,
    const unsigned short* __restrict__ Vt,
    float* __restrict__ A0,      // split-0 unnormalized partial [SEQ][H_DIM]
    float* __restrict__ A1,      // split-1 unnormalized partial
    float* __restrict__ Mp,      // [2][NH][SEQ] running max
    float* __restrict__ Lp) {    // [2][NH][SEQ] running sum
  __shared__ unsigned short Ks[KVT * HD];  // 16KB, swizzled
  __shared__ unsigned short Vs[HD * KVT];  // 16KB, swizzled
  const int tid = threadIdx.x, lane = tid & 63, wid = tid >> 6;
  const int g = lane >> 4;    // lane quarter
  const int qi = lane & 15;   // q within wave tile
  // XCD head-grouping: 4 heads per XCD; both splits of a (h,qt) adjacent
  const int id = blockIdx.x;
  const int xcd = id & 7, slot = id >> 3;       // slot 0..127
  const int h = xcd * 4 + (slot >> 5);
  const int rem = slot & 31;
  const int qt = rem >> 1;
  const int split = rem & 1;
  const int kt0 = split * NT2;
  const int q0 = qt * 64 + wid * 16;

  // Q fragments (B-operand), pre-scaled by 1/sqrt(d)
  short8 qf[4];
#pragma unroll
  for (int c = 0; c < 4; ++c) {
    short8 q = *reinterpret_cast<const short8*>(
        QKV + (size_t)(q0 + qi) * W3H + h * HD + c * 32 + g * 8);
    short8 t;
#pragma unroll
    for (int j = 0; j < 8; ++j) t[j] = (short)f2b(b2f((unsigned short)q[j]) * ATTN_SCALE);
    qf[c] = t;
  }

  float m_r = -1e30f, l_r = 0.f;
  f32x4 acc_o[8] = {};   // acc_o[nd]: rows d=nd*16+g*4+r, col q=qi

  const char* Kh = (const char*)(Kb + (size_t)h * KVL * HD);
  const char* Vh = (const char*)(Vt + (size_t)h * HD * KVL);

  short8 rK[4], rV[4];  // reg-staged next tile (pre-swizzled source addressing)

#define LOADR(t)                                                               \
  {                                                                            \
    _Pragma("unroll") for (int i = 0; i < 4; ++i) {                            \
      int c = wid * 4 + i;                                                     \
      int krow = c * 4 + (lane >> 4);                                          \
      int klcb = (16 * (lane & 15)) ^ ((krow & 7) << 4);                       \
      rK[i] = *reinterpret_cast<const short8*>(                                \
          Kh + (size_t)((t) * KVT + krow) * 256 + klcb);                       \
      int vrow = c * 8 + (lane >> 3);                                          \
      int vlcb = (16 * (lane & 7)) ^ ((vrow & 7) << 4);                        \
      rV[i] = *reinterpret_cast<const short8*>(                                \
          Vh + (size_t)vrow * (KVL * 2) + (size_t)(t) * 128 + vlcb);           \
    }                                                                          \
  }
#define WRITE_LDS()                                                            \
  {                                                                            \
    _Pragma("unroll") for (int i = 0; i < 4; ++i) {                            \
      *reinterpret_cast<short8*>((char*)Ks + (wid * 4 + i) * 1024 + lane * 16) = rK[i]; \
      *reinterpret_cast<short8*>((char*)Vs + (wid * 4 + i) * 1024 + lane * 16) = rV[i]; \
    }                                                                          \
  }

  LOADR(kt0);
  WRITE_LDS();          // compiler inserts vmcnt wait on data dep
  __syncthreads();      // tile kt0 visible

  // bpermute byte-indices (loop-invariant): pull from lanes (2*(g&1))*16+qi and +16
  const int i0 = ((2 * (g & 1) + 0) * 16 + qi) * 4;
  const int i1 = ((2 * (g & 1) + 1) * 16 + qi) * 4;

  for (int kt = 0; kt < NT2; ++kt) {
    if (kt + 1 < NT2) LOADR(kt0 + kt + 1);  // in flight across the compute phase

    // S^T = K Q^T : s[n] has col=q(=qi), row kv = n*16 + g*4 + r
    f32x4 s[4] = {};
#pragma unroll
    for (int n = 0; n < 4; ++n) {
      int row = n * 16 + qi;
#pragma unroll
      for (int c = 0; c < 4; ++c) {
        int cb = (c * 32 + g * 8) * 2;
        short8 kf = *reinterpret_cast<const short8*>(
            (const char*)Ks + row * 256 + (cb ^ ((row & 7) << 4)));
        s[n] = __builtin_amdgcn_mfma_f32_16x16x32_bf16(kf, qf[c], s[n], 0, 0, 0);
      }
    }

    // online softmax for q=qi: in-lane over 16 kv + cross-quarter (2 shfl)
    float t0 = s[0][0];
#pragma unroll
    for (int n = 0; n < 4; ++n)
#pragma unroll
      for (int r = 0; r < 4; ++r) t0 = fmaxf(t0, s[n][r]);
    t0 = fmaxf(t0, __shfl_xor(t0, 16, 64));
    t0 = fmaxf(t0, __shfl_xor(t0, 32, 64));
    int ok = (t0 <= m_r + 8.0f);
    if (!__all(ok)) {
      float mn = fmaxf(m_r, t0);
      float alpha = __expf(m_r - mn);
      l_r *= alpha;
      m_r = mn;
#pragma unroll
      for (int nd = 0; nd < 8; ++nd) acc_o[nd] *= alpha;
    }
    float p[4][4];
    float sum = 0.f;
#pragma unroll
    for (int n = 0; n < 4; ++n)
#pragma unroll
      for (int r = 0; r < 4; ++r) {
        p[n][r] = __expf(s[n][r] - m_r);
        sum += p[n][r];
      }
    sum += __shfl_xor(sum, 16, 64);
    sum += __shfl_xor(sum, 32, 64);
    l_r += sum;

    // pack p -> bf16 pairs: pr[n][rr] = {p[n][2rr] lo, p[n][2rr+1] hi}
    unsigned pr[4][2];
#pragma unroll
    for (int n = 0; n < 4; ++n)
#pragma unroll
      for (int rr = 0; rr < 2; ++rr) {
        union { __hip_bfloat162 b; unsigned u; } cv;
        cv.b = __float22bfloat162_rn(make_float2(p[n][2 * rr], p[n][2 * rr + 1]));
        pr[n][rr] = cv.u;
      }

#pragma unroll
    for (int kc = 0; kc < 2; ++kc) {
      // pull both n-halves, select by target's g>=2 (n_src = 2kc + (g>>1))
      int a0 = __builtin_amdgcn_ds_bpermute(i0, (int)pr[2 * kc][0]);
      int b0 = __builtin_amdgcn_ds_bpermute(i0, (int)pr[2 * kc + 1][0]);
      int a1 = __builtin_amdgcn_ds_bpermute(i0, (int)pr[2 * kc][1]);
      int b1 = __builtin_amdgcn_ds_bpermute(i0, (int)pr[2 * kc + 1][1]);
      int a2 = __builtin_amdgcn_ds_bpermute(i1, (int)pr[2 * kc][0]);
      int b2 = __builtin_amdgcn_ds_bpermute(i1, (int)pr[2 * kc + 1][0]);
      int a3 = __builtin_amdgcn_ds_bpermute(i1, (int)pr[2 * kc][1]);
      int b3 = __builtin_amdgcn_ds_bpermute(i1, (int)pr[2 * kc + 1][1]);
      union { int i[4]; short8 s8; } pv;
      pv.i[0] = (g < 2) ? a0 : b0;
      pv.i[1] = (g < 2) ? a1 : b1;
      pv.i[2] = (g < 2) ? a2 : b2;
      pv.i[3] = (g < 2) ? a3 : b3;

      // O^T += V^T P^T : acc_o[nd] rows d, col q
#pragma unroll
      for (int nd = 0; nd < 8; ++nd) {
        int row = nd * 16 + qi;
        int cb = kc * 64 + g * 16;
        short8 vf = *reinterpret_cast<const short8*>(
            (const char*)Vs + row * 128 + (cb ^ ((row & 7) << 4)));
        acc_o[nd] = __builtin_amdgcn_mfma_f32_16x16x32_bf16(vf, pv.s8, acc_o[nd], 0, 0, 0);
      }
    }

    __syncthreads();  // all waves done reading tile kt; rK/rV loads landed under compute
    if (kt + 1 < NT2) {
      WRITE_LDS();
      __syncthreads();  // tile kt+1 visible
    }
  }

  // epilogue: unnormalized partial (row q=q0+qi, cols d=nd*16+g*4..+3) + m,l
  float* Op = split ? A1 : A0;
  float* orow = Op + (size_t)(q0 + qi) * H_DIM + h * HD;
#pragma unroll
  for (int nd = 0; nd < 8; ++nd)
    *reinterpret_cast<float4*>(orow + nd * 16 + g * 4) =
        *reinterpret_cast<const float4*>(&acc_o[nd]);
  if (g == 0) {
    int q = q0 + qi;
    Mp[split * (NH * SEQ) + h * SEQ + q] = m_r;
    Lp[split * (NH * SEQ) + h * SEQ + q] = l_r;
  }
#undef LOADR
#undef WRITE_LDS
}

// ---------------- combine the two KV-splits ----------------
__global__ void k_combine(const float* __restrict__ A1, const float* __restrict__ Mp,
                          const float* __restrict__ Lp, float* __restrict__ out) {
  int i4 = blockIdx.x * 256 + threadIdx.x;  // < SEQ*H_DIM/4
  int q = i4 >> 10;                          // H_DIM/4 = 1024 float4 per row
  int c4 = i4 & 1023;
  int h = c4 >> 5;                           // 32 float4 per head
  float m0 = Mp[h * SEQ + q], m1 = Mp[NH * SEQ + h * SEQ + q];
  float l0 = Lp[h * SEQ + q], l1 = Lp[NH * SEQ + h * SEQ + q];
  float M = fmaxf(m0, m1);
  float w0 = __expf(m0 - M), w1 = __expf(m1 - M);
  float inv = 1.0f / (w0 * l0 + w1 * l1);
  float4 a0 = reinterpret_cast<const float4*>(out)[i4];
  float4 a1 = reinterpret_cast<const float4*>(A1)[i4];
  float4 o;
  o.x = (w0 * a0.x + w1 * a1.x) * inv;
  o.y = (w0 * a0.y + w1 * a1.y) * inv;
  o.z = (w0 * a0.z + w1 * a1.z) * inv;
  o.w = (w0 * a0.w + w1 * a1.w) * inv;
  reinterpret_cast<float4*>(out)[i4] = o;
}

extern "C" void kernel_launch(void* const* d_in, const int* in_sizes, int n_in,
                              void* d_out, int out_size, void* d_ws, size_t ws_size,
                              hipStream_t stream) {
  const float* X = (const float*)d_in[0];
  const float* W = (const float*)d_in[1];
  const float* cK = (const float*)d_in[2];
  const float* cV = (const float*)d_in[3];
  float* out = (float*)d_out;
  char* ws = (char*)d_ws;

  // ws: Xb[0,8M) QKVb[8M,32M) Wb/Kb[32M,72M) Vt[72M,112M) A1[112M,128M)
  // Mp/Lp alias Xb's first 512K — Xb is dead after the GEMM, k_attn runs after it,
  // and k_cvt fully rewrites Xb every call => deterministic across replays.
  unsigned short* Xb = (unsigned short*)(ws);
  float* Mp = (float*)(ws);
  float* Lp = (float*)(ws + (256 << 10));
  unsigned short* QKVb = (unsigned short*)(ws + ((size_t)8 << 20));
  unsigned short* Wb = (unsigned short*)(ws + ((size_t)32 << 20));
  unsigned short* Kb = (unsigned short*)(ws + ((size_t)32 << 20));
  unsigned short* Vt = (unsigned short*)(ws + ((size_t)72 << 20));
  float* A1 = (float*)(ws + ((size_t)112 << 20));

  k_cvt<<<(SEQ * H_DIM / 4) / 256, 256, 0, stream>>>(X, Xb, SEQ * H_DIM / 4);
  k_cvt<<<(W3H * H_DIM / 4) / 256, 256, 0, stream>>>(W, Wb, W3H * H_DIM / 4);

  dim3 gg(W3H / BN, SEQ / BM);
  k_gemm_qkv<<<gg, 256, 0, stream>>>(Xb, Wb, QKVb);

  k_build_k<<<(NH * KVL * HD / 4) / 256, 256, 0, stream>>>(cK, QKVb, Kb);
  dim3 gv(KVL / 64, NH);
  k_build_vt<<<gv, 256, 0, stream>>>(cV, QKVb, Vt);

  k_attn<<<SEQ / 64 * NH * 2, 256, 0, stream>>>(QKVb, Kb, Vt, out, A1, Mp, Lp);
  k_combine<<<(SEQ * H_DIM / 4) / 256, 256, 0, stream>>>(A1, Mp, Lp, out);
}

// Round 7
// 351.130 us; speedup vs baseline: 1.2792x; 1.1061x over previous
//
#include <hip/hip_runtime.h>
#include <hip/hip_bf16.h>
#include <stdint.h>

#define H_DIM 4096
#define NH 32
#define HD 128
#define SEQ 1024
#define CTX 4096
#define KVL (CTX + SEQ)      // 5120
#define W3H (3 * H_DIM)      // 12288
#define ATTN_SCALE 0.08838834764831845f

typedef short short8 __attribute__((ext_vector_type(8)));
typedef float f32x4 __attribute__((ext_vector_type(4)));

// async global->LDS, 16B per lane; LDS dest must be wave-uniform base (HW adds lane*16)
#define GLOAD_LDS16(g, l)                                             \
  __builtin_amdgcn_global_load_lds(                                   \
      (const __attribute__((address_space(1))) void*)(g),             \
      (__attribute__((address_space(3))) void*)(l), 16, 0, 0)

__device__ __forceinline__ unsigned short f2b(float f) {
  union { float f; unsigned u; } v; v.f = f;
  return (unsigned short)((v.u + 0x7FFFu + ((v.u >> 16) & 1u)) >> 16);
}
__device__ __forceinline__ float b2f(unsigned short u) {
  union { unsigned u; float f; } v; v.u = ((unsigned)u) << 16;
  return v.f;
}

// ---------------- f32 -> bf16 convert (vectorized) ----------------
__global__ void k_cvt(const float* __restrict__ s, unsigned short* __restrict__ d, int n4) {
  int i = blockIdx.x * blockDim.x + threadIdx.x;
  if (i >= n4) return;
  float4 v = reinterpret_cast<const float4*>(s)[i];
  ushort4 o;
  o.x = f2b(v.x); o.y = f2b(v.y); o.z = f2b(v.z); o.w = f2b(v.w);
  reinterpret_cast<ushort4*>(d)[i] = o;
}

// ---------------- QKV GEMM: C[m][n] = sum_k A[m][k]*B[n][k] ----------------
#define BM 128
#define BN 128
#define BK 64
__global__ __launch_bounds__(256, 2) void k_gemm_qkv(
    const unsigned short* __restrict__ A,
    const unsigned short* __restrict__ B,
    unsigned short* __restrict__ C) {
  __shared__ unsigned short As[BM * BK];
  __shared__ unsigned short Bs[BN * BK];
  const int tid = threadIdx.x;
  const int lane = tid & 63;
  const int wid = tid >> 6;
  const int bn = blockIdx.x, bm = blockIdx.y;
  const int wr = wid >> 1, wc = wid & 1;

  f32x4 acc[4][4] = {};

  const int lrow = lane >> 3;
  const int lcol = (lane & 7) * 8;
  const unsigned short* ga = A + (size_t)(bm * BM + wid * 32 + lrow) * H_DIM + lcol;
  const unsigned short* gb = B + (size_t)(bn * BN + wid * 32 + lrow) * H_DIM + lcol;

  for (int kt = 0; kt < H_DIM / BK; ++kt) {
    __syncthreads();
    const unsigned short* gak = ga + kt * BK;
    const unsigned short* gbk = gb + kt * BK;
#pragma unroll
    for (int i = 0; i < 4; ++i) {
      GLOAD_LDS16(gak + i * 8 * H_DIM, As + (wid * 4 + i) * 512);
      GLOAD_LDS16(gbk + i * 8 * H_DIM, Bs + (wid * 4 + i) * 512);
    }
    __syncthreads();
#pragma unroll
    for (int kk = 0; kk < 2; ++kk) {
      short8 af[4], bfr[4];
#pragma unroll
      for (int m = 0; m < 4; ++m)
        af[m] = *reinterpret_cast<const short8*>(
            As + (wr * 64 + m * 16 + (lane & 15)) * BK + kk * 32 + (lane >> 4) * 8);
#pragma unroll
      for (int n = 0; n < 4; ++n)
        bfr[n] = *reinterpret_cast<const short8*>(
            Bs + (wc * 64 + n * 16 + (lane & 15)) * BK + kk * 32 + (lane >> 4) * 8);
#pragma unroll
      for (int m = 0; m < 4; ++m)
#pragma unroll
        for (int n = 0; n < 4; ++n)
          acc[m][n] = __builtin_amdgcn_mfma_f32_16x16x32_bf16(af[m], bfr[n], acc[m][n], 0, 0, 0);
    }
  }
  const int r0 = bm * BM + wr * 64 + (lane >> 4) * 4;
  const int c0 = bn * BN + wc * 64 + (lane & 15);
#pragma unroll
  for (int m = 0; m < 4; ++m)
#pragma unroll
    for (int n = 0; n < 4; ++n)
#pragma unroll
      for (int r = 0; r < 4; ++r)
        C[(size_t)(r0 + m * 16 + r) * W3H + c0 + n * 16] = f2b(acc[m][n][r]);
}

// ---------------- build Kb[h][kv][d] bf16 ----------------
__global__ void k_build_k(const float* __restrict__ cK, const unsigned short* __restrict__ QKV,
                          unsigned short* __restrict__ Kb) {
  int idx = (blockIdx.x * 256 + threadIdx.x) * 4;
  if (idx >= NH * KVL * HD) return;
  int h = idx / (KVL * HD);
  int rem = idx % (KVL * HD);
  int kv = rem / HD;
  int d = rem % HD;
  ushort4 o;
  if (kv < CTX) {
    float4 v = *reinterpret_cast<const float4*>(cK + ((size_t)kv * NH + h) * HD + d);
    o.x = f2b(v.x); o.y = f2b(v.y); o.z = f2b(v.z); o.w = f2b(v.w);
  } else {
    o = *reinterpret_cast<const ushort4*>(QKV + (size_t)(kv - CTX) * W3H + H_DIM + h * HD + d);
  }
  *reinterpret_cast<ushort4*>(Kb + idx) = o;
}

// ---------------- build Vt[h][d][kv] bf16 (transposed) ----------------
__global__ void k_build_vt(const float* __restrict__ cV, const unsigned short* __restrict__ QKV,
                           unsigned short* __restrict__ Vt) {
  __shared__ unsigned short T[HD][66];
  const int h = blockIdx.y;
  const int kt = blockIdx.x;
  const int t = threadIdx.x;
#pragma unroll
  for (int e = 0; e < 8; ++e) {
    int idx = (t + e * 256) * 4;
    int kvl = idx >> 7;
    int d = idx & 127;
    int kv = kt * 64 + kvl;
    unsigned short a, b, c, w;
    if (kv < CTX) {
      float4 v = *reinterpret_cast<const float4*>(cV + ((size_t)kv * NH + h) * HD + d);
      a = f2b(v.x); b = f2b(v.y); c = f2b(v.z); w = f2b(v.w);
    } else {
      ushort4 u = *reinterpret_cast<const ushort4*>(QKV + (size_t)(kv - CTX) * W3H + 2 * H_DIM + h * HD + d);
      a = u.x; b = u.y; c = u.z; w = u.w;
    }
    T[d][kvl] = a; T[d + 1][kvl] = b; T[d + 2][kvl] = c; T[d + 3][kvl] = w;
  }
  __syncthreads();
#pragma unroll
  for (int e = 0; e < 8; ++e) {
    int idx = (t + e * 256) * 4;
    int d = idx >> 6;
    int kv0 = idx & 63;
    ushort4 o;
    o.x = T[d][kv0]; o.y = T[d][kv0 + 1]; o.z = T[d][kv0 + 2]; o.w = T[d][kv0 + 3];
    *reinterpret_cast<ushort4*>(Vt + ((size_t)h * HD + d) * KVL + kt * 64 + kv0) = o;
  }
}

// ---------------- flash attention v3 ----------------
// 32 q per wave (2 halves): every K/V LDS read feeds 2 MFMAs.
// Double-buffered K/V in LDS -> ONE barrier per iteration.
// S^T = mfma(K,Q): lane owns col q; in-lane softmax, 2 shfl per reduce.
// O^T = mfma(V^T,P^T); P repacked in-register via bpermute (pull both halves, cndmask).
#define KVT 64
#define NT (KVL / KVT)   // 80
#define NT2 (NT / 2)     // 40 per split
__global__ __launch_bounds__(256, 2) void k_attn(
    const unsigned short* __restrict__ QKV,
    const unsigned short* __restrict__ Kb,
    const unsigned short* __restrict__ Vt,
    float* __restrict__ A0,      // split-0 unnormalized partial [SEQ][H_DIM]
    float* __restrict__ A1,      // split-1 unnormalized partial
    float* __restrict__ Mp,      // [2][NH][SEQ] running max
    float* __restrict__ Lp) {    // [2][NH][SEQ] running sum
  __shared__ unsigned short Ks[2][KVT * HD];  // 2x16KB, swizzled
  __shared__ unsigned short Vs[2][KVT * HD];  // 2x16KB, swizzled
  const int tid = threadIdx.x, lane = tid & 63, wid = tid >> 6;
  const int g = lane >> 4;    // lane quarter
  const int qi = lane & 15;   // q within 16-row half
  // XCD head-grouping: 4 heads per XCD (512 blocks total)
  const int id = blockIdx.x;
  const int xcd = id & 7, slot = id >> 3;       // slot 0..63
  const int h = xcd * 4 + (slot >> 4);
  const int rem = slot & 15;
  const int qt = rem >> 1;                      // 0..7 (128-q tiles)
  const int split = rem & 1;
  const int kt0 = split * NT2;
  const int q0 = qt * 128 + wid * 32;

  // Q fragments (B-operand) for both halves, pre-scaled by 1/sqrt(d)
  short8 qf[2][4];
#pragma unroll
  for (int hf = 0; hf < 2; ++hf)
#pragma unroll
    for (int c = 0; c < 4; ++c) {
      short8 q = *reinterpret_cast<const short8*>(
          QKV + (size_t)(q0 + hf * 16 + qi) * W3H + h * HD + c * 32 + g * 8);
      short8 t;
#pragma unroll
      for (int j = 0; j < 8; ++j) t[j] = (short)f2b(b2f((unsigned short)q[j]) * ATTN_SCALE);
      qf[hf][c] = t;
    }

  float m_r[2] = {-1e30f, -1e30f}, l_r[2] = {0.f, 0.f};
  f32x4 acc_o[2][8] = {};   // [half][nd]: rows d=nd*16+g*4+r, col q

  const char* Kh = (const char*)(Kb + (size_t)h * KVL * HD);
  const char* Vh = (const char*)(Vt + (size_t)h * HD * KVL);

  short8 rK[4], rV[4];  // reg-staged next tile (pre-swizzled source addressing)

#define LOADR(t)                                                               \
  {                                                                            \
    _Pragma("unroll") for (int i = 0; i < 4; ++i) {                            \
      int c = wid * 4 + i;                                                     \
      int krow = c * 4 + (lane >> 4);                                          \
      int klcb = (16 * (lane & 15)) ^ ((krow & 7) << 4);                       \
      rK[i] = *reinterpret_cast<const short8*>(                                \
          Kh + (size_t)((t) * KVT + krow) * 256 + klcb);                       \
      int vrow = c * 8 + (lane >> 3);                                          \
      int vlcb = (16 * (lane & 7)) ^ ((vrow & 7) << 4);                        \
      rV[i] = *reinterpret_cast<const short8*>(                                \
          Vh + (size_t)vrow * (KVL * 2) + (size_t)(t) * 128 + vlcb);           \
    }                                                                          \
  }
#define WRITE_LDS(b)                                                           \
  {                                                                            \
    _Pragma("unroll") for (int i = 0; i < 4; ++i) {                            \
      *reinterpret_cast<short8*>((char*)Ks[b] + (wid * 4 + i) * 1024 + lane * 16) = rK[i]; \
      *reinterpret_cast<short8*>((char*)Vs[b] + (wid * 4 + i) * 1024 + lane * 16) = rV[i]; \
    }                                                                          \
  }

  LOADR(kt0);
  WRITE_LDS(0);         // compiler inserts vmcnt wait on data dep
  __syncthreads();      // tile kt0 visible

  // bpermute byte-indices (loop-invariant)
  const int i0 = ((2 * (g & 1) + 0) * 16 + qi) * 4;
  const int i1 = ((2 * (g & 1) + 1) * 16 + qi) * 4;

  for (int kt = 0; kt < NT2; ++kt) {
    const int cur = kt & 1;
    if (kt + 1 < NT2) LOADR(kt0 + kt + 1);  // in flight across the compute phase

    // S^T = K Q^T for both halves: each kf read feeds 2 MFMAs
    f32x4 s[2][4] = {};
#pragma unroll
    for (int n = 0; n < 4; ++n) {
      int row = n * 16 + qi;
#pragma unroll
      for (int c = 0; c < 4; ++c) {
        int cb = (c * 32 + g * 8) * 2;
        short8 kf = *reinterpret_cast<const short8*>(
            (const char*)Ks[cur] + row * 256 + (cb ^ ((row & 7) << 4)));
        s[0][n] = __builtin_amdgcn_mfma_f32_16x16x32_bf16(kf, qf[0][c], s[0][n], 0, 0, 0);
        s[1][n] = __builtin_amdgcn_mfma_f32_16x16x32_bf16(kf, qf[1][c], s[1][n], 0, 0, 0);
      }
    }

    // online softmax per half; combined defer-max vote
    float p[2][4][4];
    int ok = 1;
    float tmax[2];
#pragma unroll
    for (int hf = 0; hf < 2; ++hf) {
      float t0 = s[hf][0][0];
#pragma unroll
      for (int n = 0; n < 4; ++n)
#pragma unroll
        for (int r = 0; r < 4; ++r) t0 = fmaxf(t0, s[hf][n][r]);
      t0 = fmaxf(t0, __shfl_xor(t0, 16, 64));
      t0 = fmaxf(t0, __shfl_xor(t0, 32, 64));
      tmax[hf] = t0;
      ok &= (t0 <= m_r[hf] + 8.0f);
    }
    if (!__all(ok)) {
#pragma unroll
      for (int hf = 0; hf < 2; ++hf) {
        float mn = fmaxf(m_r[hf], tmax[hf]);
        float alpha = __expf(m_r[hf] - mn);
        l_r[hf] *= alpha;
        m_r[hf] = mn;
#pragma unroll
        for (int nd = 0; nd < 8; ++nd) acc_o[hf][nd] *= alpha;
      }
    }
#pragma unroll
    for (int hf = 0; hf < 2; ++hf) {
      float sum = 0.f;
#pragma unroll
      for (int n = 0; n < 4; ++n)
#pragma unroll
        for (int r = 0; r < 4; ++r) {
          p[hf][n][r] = __expf(s[hf][n][r] - m_r[hf]);
          sum += p[hf][n][r];
        }
      sum += __shfl_xor(sum, 16, 64);
      sum += __shfl_xor(sum, 32, 64);
      l_r[hf] += sum;
    }

    // pack p -> bf16 pairs per half
    unsigned pr[2][4][2];
#pragma unroll
    for (int hf = 0; hf < 2; ++hf)
#pragma unroll
      for (int n = 0; n < 4; ++n)
#pragma unroll
        for (int rr = 0; rr < 2; ++rr) {
          union { __hip_bfloat162 b; unsigned u; } cv;
          cv.b = __float22bfloat162_rn(make_float2(p[hf][n][2 * rr], p[hf][n][2 * rr + 1]));
          pr[hf][n][rr] = cv.u;
        }

#pragma unroll
    for (int kc = 0; kc < 2; ++kc) {
      // repack both halves' P fragments (pull both n-halves, select by g>=2)
      short8 pv[2];
#pragma unroll
      for (int hf = 0; hf < 2; ++hf) {
        int a0 = __builtin_amdgcn_ds_bpermute(i0, (int)pr[hf][2 * kc][0]);
        int b0 = __builtin_amdgcn_ds_bpermute(i0, (int)pr[hf][2 * kc + 1][0]);
        int a1 = __builtin_amdgcn_ds_bpermute(i0, (int)pr[hf][2 * kc][1]);
        int b1 = __builtin_amdgcn_ds_bpermute(i0, (int)pr[hf][2 * kc + 1][1]);
        int a2 = __builtin_amdgcn_ds_bpermute(i1, (int)pr[hf][2 * kc][0]);
        int b2 = __builtin_amdgcn_ds_bpermute(i1, (int)pr[hf][2 * kc + 1][0]);
        int a3 = __builtin_amdgcn_ds_bpermute(i1, (int)pr[hf][2 * kc][1]);
        int b3 = __builtin_amdgcn_ds_bpermute(i1, (int)pr[hf][2 * kc + 1][1]);
        union { int i[4]; short8 s8; } u;
        u.i[0] = (g < 2) ? a0 : b0;
        u.i[1] = (g < 2) ? a1 : b1;
        u.i[2] = (g < 2) ? a2 : b2;
        u.i[3] = (g < 2) ? a3 : b3;
        pv[hf] = u.s8;
      }

      // O^T += V^T P^T : each vf read feeds 2 MFMAs
#pragma unroll
      for (int nd = 0; nd < 8; ++nd) {
        int row = nd * 16 + qi;
        int cb = kc * 64 + g * 16;
        short8 vf = *reinterpret_cast<const short8*>(
            (const char*)Vs[cur] + row * 128 + (cb ^ ((row & 7) << 4)));
        acc_o[0][nd] = __builtin_amdgcn_mfma_f32_16x16x32_bf16(vf, pv[0], acc_o[0][nd], 0, 0, 0);
        acc_o[1][nd] = __builtin_amdgcn_mfma_f32_16x16x32_bf16(vf, pv[1], acc_o[1][nd], 0, 0, 0);
      }
    }

    // write next tile into the other buffer (its old contents were consumed
    // before the PREVIOUS barrier), then one barrier
    if (kt + 1 < NT2) WRITE_LDS(cur ^ 1);
    __syncthreads();
  }

  // epilogue: unnormalized partial + m,l per half
  float* Op = split ? A1 : A0;
#pragma unroll
  for (int hf = 0; hf < 2; ++hf) {
    float* orow = Op + (size_t)(q0 + hf * 16 + qi) * H_DIM + h * HD;
#pragma unroll
    for (int nd = 0; nd < 8; ++nd)
      *reinterpret_cast<float4*>(orow + nd * 16 + g * 4) =
          *reinterpret_cast<const float4*>(&acc_o[hf][nd]);
    if (g == 0) {
      int q = q0 + hf * 16 + qi;
      Mp[split * (NH * SEQ) + h * SEQ + q] = m_r[hf];
      Lp[split * (NH * SEQ) + h * SEQ + q] = l_r[hf];
    }
  }
#undef LOADR
#undef WRITE_LDS
}

// ---------------- combine the two KV-splits ----------------
__global__ void k_combine(const float* __restrict__ A1, const float* __restrict__ Mp,
                          const float* __restrict__ Lp, float* __restrict__ out) {
  int i4 = blockIdx.x * 256 + threadIdx.x;  // < SEQ*H_DIM/4
  int q = i4 >> 10;                          // H_DIM/4 = 1024 float4 per row
  int c4 = i4 & 1023;
  int h = c4 >> 5;                           // 32 float4 per head
  float m0 = Mp[h * SEQ + q], m1 = Mp[NH * SEQ + h * SEQ + q];
  float l0 = Lp[h * SEQ + q], l1 = Lp[NH * SEQ + h * SEQ + q];
  float M = fmaxf(m0, m1);
  float w0 = __expf(m0 - M), w1 = __expf(m1 - M);
  float inv = 1.0f / (w0 * l0 + w1 * l1);
  float4 a0 = reinterpret_cast<const float4*>(out)[i4];
  float4 a1 = reinterpret_cast<const float4*>(A1)[i4];
  float4 o;
  o.x = (w0 * a0.x + w1 * a1.x) * inv;
  o.y = (w0 * a0.y + w1 * a1.y) * inv;
  o.z = (w0 * a0.z + w1 * a1.z) * inv;
  o.w = (w0 * a0.w + w1 * a1.w) * inv;
  reinterpret_cast<float4*>(out)[i4] = o;
}

extern "C" void kernel_launch(void* const* d_in, const int* in_sizes, int n_in,
                              void* d_out, int out_size, void* d_ws, size_t ws_size,
                              hipStream_t stream) {
  const float* X = (const float*)d_in[0];
  const float* W = (const float*)d_in[1];
  const float* cK = (const float*)d_in[2];
  const float* cV = (const float*)d_in[3];
  float* out = (float*)d_out;
  char* ws = (char*)d_ws;

  // ws: Xb[0,8M) QKVb[8M,32M) Wb/Kb[32M,72M) Vt[72M,112M) A1[112M,128M)
  // Mp/Lp alias Xb's first 512K — Xb is dead after the GEMM, k_attn runs after it,
  // and k_cvt fully rewrites Xb every call => deterministic across replays.
  unsigned short* Xb = (unsigned short*)(ws);
  float* Mp = (float*)(ws);
  float* Lp = (float*)(ws + (256 << 10));
  unsigned short* QKVb = (unsigned short*)(ws + ((size_t)8 << 20));
  unsigned short* Wb = (unsigned short*)(ws + ((size_t)32 << 20));
  unsigned short* Kb = (unsigned short*)(ws + ((size_t)32 << 20));
  unsigned short* Vt = (unsigned short*)(ws + ((size_t)72 << 20));
  float* A1 = (float*)(ws + ((size_t)112 << 20));

  k_cvt<<<(SEQ * H_DIM / 4) / 256, 256, 0, stream>>>(X, Xb, SEQ * H_DIM / 4);
  k_cvt<<<(W3H * H_DIM / 4) / 256, 256, 0, stream>>>(W, Wb, W3H * H_DIM / 4);

  dim3 gg(W3H / BN, SEQ / BM);
  k_gemm_qkv<<<gg, 256, 0, stream>>>(Xb, Wb, QKVb);

  k_build_k<<<(NH * KVL * HD / 4) / 256, 256, 0, stream>>>(cK, QKVb, Kb);
  dim3 gv(KVL / 64, NH);
  k_build_vt<<<gv, 256, 0, stream>>>(cV, QKVb, Vt);

  k_attn<<<SEQ / 128 * NH * 2, 256, 0, stream>>>(QKVb, Kb, Vt, out, A1, Mp, Lp);
  k_combine<<<(SEQ * H_DIM / 4) / 256, 256, 0, stream>>>(A1, Mp, Lp, out);
}